// Round 5
// baseline (204.172 us; speedup 1.0000x reference)
//
#include <hip/hip_runtime.h>
#include <stdint.h>

// FlowNet correlation: out[b, dy*9+dx, y, x] = (1/256) sum_c x1[b,c,y,x] * x2[b,c,y+dy-4,x+dx-4]
// B=4 C=256 H=W=128, 9x9 displacements, zero padding.
//
// Round-5 design:
//  - Both x1 and x2 staged via __builtin_amdgcn_global_load_lds (width 16): no staging
//    registers, no commit phase, HW lane-contiguous LDS writes (conflict-free).
//  - Distance-2 prefetch with 3 LDS buffers: chunk k's loads issued 2 iterations early
//    (~2 compute phases > HBM latency). Raw s_barrier + explicit s_waitcnt vmcnt(4)
//    per chunk (vmcnt(0) only on the last iteration) -- AITER-style, never full drain.
//  - Unpadded layouts (required by global_load_lds): x2 rows stride 24 dw, x1 stride 16 dw.
//    Bank math: b128 reads are phase-even (2 lanes/bank/phase) -> conflict-free.
//  - OOB / pad slots source from a 64-B zero page in d_ws (hipMemsetAsync each launch)
//    so every wave issues exactly NSLOT load instructions per chunk (deterministic vmcnt).
//  - Kept from r2-r4: 3 waves/block (one dy per wave), acc[9][4] regs, XCD swizzle
//    (g-siblings +8 apart -> same XCD L2; FETCH 464->180 MB validated).

#define MD 4
constexpr int Bc = 4, Cc = 256, Hc = 128, Wc = 128;
constexpr int HW = Hc * Wc;
constexpr int TH = 16, TW = 16;
constexpr int CC = 4;                    // channels per chunk
constexpr int SROWS = 18, SCOLS = 24;    // x2 staged halo tile
constexpr int X2_SLOTS = CC * SROWS * (SCOLS / 4);   // 432 float4 slots
constexpr int X2_PAD   = 448;                        // x2 region padded (16 pad slots)
constexpr int X1_SLOTS = CC * TH * (TW / 4);         // 256 float4 slots
constexpr int SL_TOT   = 768;                        // 448 + 256 = 704, padded to 4*192
constexpr int BUF_DW   = SL_TOT * 4;                 // 3072 dw = 12 KB per buffer
constexpr int X1OFF    = X2_PAD * 4;                 // 1792 dw: x1 region start
constexpr int NTHR  = 192;
constexpr int NSLOT = 4;                 // slots per thread per chunk (uniform)
constexpr int NK = Cc / CC;              // 64 chunks

__device__ __forceinline__ void async16(const void* g, const void* l) {
    __builtin_amdgcn_global_load_lds(
        (const __attribute__((address_space(1))) unsigned int*)g,
        (__attribute__((address_space(3))) unsigned int*)l, 16, 0, 0);
}

__global__ __launch_bounds__(NTHR, 2)
void corr_kernel(const float* __restrict__ x1, const float* __restrict__ x2,
                 const float* __restrict__ zpage, float* __restrict__ out)
{
    __shared__ float stg[3 * BUF_DW];    // 36864 B

    const int tid  = threadIdx.x;
    const int w    = tid >> 6;           // wave id = local dy
    const int lane = tid & 63;
    const int gy   = lane >> 2;          // 0..15 tile row
    const int gx   = lane & 3;           // 0..3  col-group (4 px)

    // XCD-aware swizzle: g-siblings of a tile differ by +8 in bid -> same XCD L2
    const int bid = blockIdx.x;
    const int q   = bid / 24;
    const int r0  = bid - q * 24;
    const int g   = r0 >> 3;             // d-group 0..2
    const int t   = q * 8 + (r0 & 7);    // tile index 0..255
    const int tx = t & 7, ty = (t >> 3) & 7, bb = t >> 6;
    const int x0 = tx * TW, y0 = ty * TH;
    const int rowbase = y0 + 3 * g - MD;

    // ---- per-thread slot descriptors: source ptr, per-chunk byte step, LDS dw offset ----
    const char* sp[NSLOT];
    int sstep[NSLOT], sloff[NSLOT];
    const size_t cbase = (size_t)bb * Cc * HW;   // channel-0 offset of this batch
    #pragma unroll
    for (int s = 0; s < NSLOT; ++s) {
        const int slot = tid + s * NTHR;
        sloff[s] = slot * 4;
        if (slot < X2_SLOTS) {
            const int cl  = slot / 108;
            const int rem = slot - cl * 108;
            const int rr  = rem / 6;
            const int gc  = rem - rr * 6;
            const int yy  = rowbase + rr;
            const int xx  = x0 - 4 + 4 * gc;
            const bool valid = ((unsigned)yy < (unsigned)Hc) && ((unsigned)xx <= (unsigned)(Wc - 4));
            sp[s]    = valid ? (const char*)(x2 + cbase + (size_t)cl * HW + yy * Wc + xx)
                             : (const char*)zpage;
            sstep[s] = valid ? (int)(CC * HW * sizeof(float)) : 0;
        } else if (slot < X2_PAD) {
            sp[s] = (const char*)zpage;  sstep[s] = 0;
        } else if (slot < X2_PAD + X1_SLOTS) {
            const int j   = slot - X2_PAD;
            const int cl  = j >> 6;
            const int py  = (j >> 2) & 15;
            const int pxg = j & 3;
            sp[s]    = (const char*)(x1 + cbase + (size_t)cl * HW + (y0 + py) * Wc + x0 + 4 * pxg);
            sstep[s] = (int)(CC * HW * sizeof(float));
        } else {
            sp[s] = (const char*)zpage;  sstep[s] = 0;
        }
    }

    float acc[9][4];
    #pragma unroll
    for (int dx = 0; dx < 9; ++dx)
        #pragma unroll
        for (int p = 0; p < 4; ++p) acc[dx][p] = 0.f;

    // ---- prologue: issue chunks 0 and 1 into buffers 0 and 1 ----
    #pragma unroll
    for (int s = 0; s < NSLOT; ++s) {
        async16(sp[s], (const void*)(&stg[0 * BUF_DW] + sloff[s]));
        sp[s] += sstep[s];
    }
    #pragma unroll
    for (int s = 0; s < NSLOT; ++s) {
        async16(sp[s], (const void*)(&stg[1 * BUF_DW] + sloff[s]));
        sp[s] += sstep[s];
    }

    int bc = 0;   // k % 3
    for (int k = 0; k < NK; ++k) {
        // wait for chunk k's loads (this wave's share); k+1's (4 instr) may stay in flight
        if (k == NK - 1) __builtin_amdgcn_s_waitcnt(0x0F70);   // vmcnt(0)
        else             __builtin_amdgcn_s_waitcnt(0x0F74);   // vmcnt(4)
        __builtin_amdgcn_s_barrier();   // all waves: chunk k loaded, chunk k-1 compute done
        __builtin_amdgcn_sched_barrier(0);
        // issue chunk k+2 into buffer (k+2)%3 (last read during compute k-1: safe)
        if (k + 2 < NK) {
            int b2 = bc + 2; if (b2 >= 3) b2 -= 3;
            float* bp2 = &stg[b2 * BUF_DW];
            #pragma unroll
            for (int s = 0; s < NSLOT; ++s) {
                async16(sp[s], (const void*)(bp2 + sloff[s]));
                sp[s] += sstep[s];
            }
        }
        // ---- compute chunk k entirely from LDS ----
        const float* bp = &stg[bc * BUF_DW];
        #pragma unroll
        for (int cl = 0; cl < CC; ++cl) {
            const float4 a4 = *(const float4*)(bp + X1OFF + cl * 256 + gy * 16 + 4 * gx);
            const float* rowp = bp + cl * (SROWS * SCOLS) + (gy + w) * SCOLS + 4 * gx;
            const float4 q0 = *(const float4*)(rowp);
            const float4 q1 = *(const float4*)(rowp + 4);
            const float4 q2 = *(const float4*)(rowp + 8);
            const float v[12] = {q0.x, q0.y, q0.z, q0.w,
                                 q1.x, q1.y, q1.z, q1.w,
                                 q2.x, q2.y, q2.z, q2.w};
            const float a[4] = {a4.x, a4.y, a4.z, a4.w};
            #pragma unroll
            for (int dx = 0; dx < 9; ++dx)
                #pragma unroll
                for (int p = 0; p < 4; ++p)
                    acc[dx][p] += a[p] * v[dx + p];
        }
        if (++bc == 3) bc = 0;
    }

    // ---- epilogue: scale and store 9 aligned float4 per thread ----
    const float inv = 1.0f / (float)Cc;
    float* ob = out + (((size_t)bb * 81 + (3 * g + w) * 9) * Hc + (y0 + gy)) * Wc + x0 + 4 * gx;
    #pragma unroll
    for (int dx = 0; dx < 9; ++dx) {
        float4 st = make_float4(acc[dx][0] * inv, acc[dx][1] * inv,
                                acc[dx][2] * inv, acc[dx][3] * inv);
        *(float4*)(ob + dx * HW) = st;
    }
}

extern "C" void kernel_launch(void* const* d_in, const int* in_sizes, int n_in,
                              void* d_out, int out_size, void* d_ws, size_t ws_size,
                              hipStream_t stream) {
    const float* x1 = (const float*)d_in[0];
    const float* x2 = (const float*)d_in[1];
    float* out = (float*)d_out;
    // 64-B zero page for OOB/pad staging sources (d_ws is re-poisoned each launch)
    hipMemsetAsync(d_ws, 0, 64, stream);
    dim3 grid(3 * 8 * 8 * Bc), block(NTHR);   // 768 blocks x 192 threads
    corr_kernel<<<grid, block, 0, stream>>>(x1, x2, (const float*)d_ws, out);
}